// Round 3
// baseline (3811.782 us; speedup 1.0000x reference)
//
#include <hip/hip_runtime.h>
#include <stdint.h>

#define BW   128      // nodes per bucket
#define NBM  625      // movie buckets  (80000/128)
#define NBU  1563     // user buckets   (ceil 200000/128)
#define CAPM 4096     // per-bucket capacity, movie (avg 3200, +15 sigma)
#define CAPU 2048     // per-bucket capacity, user  (avg 1280, +21 sigma)

// ---------------- edge binning: bucket-major edge lists, both directions ----------------
// Bm record: (dst&127)<<24 | src   (bucket = dst>>7)
// Bu record: (src&127)<<24 | dst   (bucket = src>>7)
__global__ __launch_bounds__(256) void bin_kernel(
    const int* __restrict__ src, const int* __restrict__ dst, int E,
    int* __restrict__ gcm, int* __restrict__ gcu,
    uint32_t* __restrict__ Bm, uint32_t* __restrict__ Bu)
{
    __shared__ int hm[NBM], hu[NBU];
    const int CH = 8192;
    int e0 = blockIdx.x * CH;
    int e1 = min(e0 + CH, E);
    int tid = threadIdx.x;
    for (int b = tid; b < NBM; b += 256) hm[b] = 0;
    for (int b = tid; b < NBU; b += 256) hu[b] = 0;
    __syncthreads();
    for (int i = e0 + tid; i < e1; i += 256) {
        atomicAdd(&hm[dst[i] >> 7], 1);
        atomicAdd(&hu[src[i] >> 7], 1);
    }
    __syncthreads();
    // reserve global space per bucket; hm/hu become running cursors (base position)
    for (int b = tid; b < NBM; b += 256) { int c = hm[b]; hm[b] = c ? atomicAdd(&gcm[b], c) : 0; }
    for (int b = tid; b < NBU; b += 256) { int c = hu[b]; hu[b] = c ? atomicAdd(&gcu[b], c) : 0; }
    __syncthreads();
    for (int i = e0 + tid; i < e1; i += 256) {
        int d = dst[i], s = src[i];
        int bm = d >> 7, bu = s >> 7;
        int pm = atomicAdd(&hm[bm], 1);
        if (pm < CAPM) Bm[(size_t)bm * CAPM + pm] = ((uint32_t)(d & 127) << 24) | (uint32_t)s;
        int pu = atomicAdd(&hu[bu], 1);
        if (pu < CAPU) Bu[(size_t)bu * CAPU + pu] = ((uint32_t)(s & 127) << 24) | (uint32_t)d;
    }
}

// ---------------- fused bucket aggregation: mean + bias + self (+relu) ----------------
// out[n,:] = relu?( mean_{edges->n} table[payload,:] + bias + self[n,:] )
template<int RELU>
__global__ __launch_bounds__(256) void agg_bucket(
    const uint32_t* __restrict__ B, const int* __restrict__ gcnt, int cap,
    const float* __restrict__ table, const float* __restrict__ self,
    const float* __restrict__ bias, float* __restrict__ out, int n_nodes)
{
    __shared__ float acc[BW * 64];
    __shared__ int cl[BW];
    int tid = threadIdx.x, lane = tid & 63, wid = tid >> 6;
    int b = blockIdx.x;
    for (int i = tid; i < BW * 64; i += 256) acc[i] = 0.f;
    if (tid < BW) cl[tid] = 0;
    __syncthreads();
    int cnt = min(gcnt[b], cap);
    const uint32_t* bp = B + (size_t)b * cap;
    int nch = (cnt + 3) >> 2;
    for (int c = wid; c < nch; c += 4) {
        int base = c * 4;
        int m = cnt - base;
        if (m >= 4) {
            uint32_t r0 = bp[base], r1 = bp[base + 1], r2 = bp[base + 2], r3 = bp[base + 3];
            float v0 = table[(size_t)(r0 & 0xFFFFFF) * 64 + lane];
            float v1 = table[(size_t)(r1 & 0xFFFFFF) * 64 + lane];
            float v2 = table[(size_t)(r2 & 0xFFFFFF) * 64 + lane];
            float v3 = table[(size_t)(r3 & 0xFFFFFF) * 64 + lane];
            atomicAdd(&acc[(r0 >> 24) * 64 + lane], v0);
            atomicAdd(&acc[(r1 >> 24) * 64 + lane], v1);
            atomicAdd(&acc[(r2 >> 24) * 64 + lane], v2);
            atomicAdd(&acc[(r3 >> 24) * 64 + lane], v3);
            if (lane == 0) {
                atomicAdd(&cl[r0 >> 24], 1); atomicAdd(&cl[r1 >> 24], 1);
                atomicAdd(&cl[r2 >> 24], 1); atomicAdd(&cl[r3 >> 24], 1);
            }
        } else {
            for (int k = 0; k < m; ++k) {
                uint32_t r = bp[base + k];
                float v = table[(size_t)(r & 0xFFFFFF) * 64 + lane];
                atomicAdd(&acc[(r >> 24) * 64 + lane], v);
                if (lane == 0) atomicAdd(&cl[r >> 24], 1);
            }
        }
    }
    __syncthreads();
    for (int n = wid; n < BW; n += 4) {
        int gn = b * BW + n;
        if (gn >= n_nodes) break;
        float inv = 1.f / fmaxf((float)cl[n], 1.f);
        float v = acc[n * 64 + lane] * inv + bias[lane] + self[(size_t)gn * 64 + lane];
        if (RELU) v = fmaxf(v, 0.f);
        out[(size_t)gn * 64 + lane] = v;
    }
}

// ---------------- tiled GEMM: Y[M,64] = X[M,K] @ W[K,64] ----------------
template<int K>
__global__ __launch_bounds__(256) void gemm_tile(
    const float* __restrict__ X, const float* __restrict__ W,
    float* __restrict__ Y, int M)
{
    __shared__ float Ws[K * 64];
    __shared__ float Xs[K][68];
    int tid = threadIdx.x;
    int row0 = blockIdx.x * 64;
    for (int i = tid; i < K * 64; i += 256) Ws[i] = W[i];
    for (int i = tid; i < 64 * K; i += 256) {
        int r = i / K, k = i - r * K;
        int gr = row0 + r;
        Xs[k][r] = (gr < M) ? X[(size_t)gr * K + k] : 0.f;
    }
    __syncthreads();
    int tr = (tid & 15) * 4;
    int tc = (tid >> 4) * 4;
    float acc[4][4] = {};
#pragma unroll 8
    for (int k = 0; k < K; ++k) {
        float4 xv = *(const float4*)&Xs[k][tr];
        float4 wv = *(const float4*)&Ws[k * 64 + tc];
        acc[0][0] += xv.x * wv.x; acc[0][1] += xv.x * wv.y; acc[0][2] += xv.x * wv.z; acc[0][3] += xv.x * wv.w;
        acc[1][0] += xv.y * wv.x; acc[1][1] += xv.y * wv.y; acc[1][2] += xv.y * wv.z; acc[1][3] += xv.y * wv.w;
        acc[2][0] += xv.z * wv.x; acc[2][1] += xv.z * wv.y; acc[2][2] += xv.z * wv.z; acc[2][3] += xv.z * wv.w;
        acc[3][0] += xv.w * wv.x; acc[3][1] += xv.w * wv.y; acc[3][2] += xv.w * wv.z; acc[3][3] += xv.w * wv.w;
    }
#pragma unroll
    for (int r = 0; r < 4; ++r) {
        int gr = row0 + tr + r;
        if (gr < M) {
            float4 o = make_float4(acc[r][0], acc[r][1], acc[r][2], acc[r][3]);
            *(float4*)&Y[(size_t)gr * 64 + tc] = o;
        }
    }
}

// ---------------- dual GEMM: Ya = X@Wa, Yb = X@Wb  (K=64, X read once) ----------------
__global__ __launch_bounds__(256) void gemm64_dual(
    const float* __restrict__ X, const float* __restrict__ Wa, const float* __restrict__ Wb,
    float* __restrict__ Ya, float* __restrict__ Yb, int M)
{
    __shared__ float Ws[64 * 128];
    __shared__ float Xs[64][68];
    int tid = threadIdx.x;
    int row0 = blockIdx.x * 64;
    for (int i = tid; i < 64 * 64; i += 256) {
        int k = i >> 6, c = i & 63;
        Ws[k * 128 + c] = Wa[i];
        Ws[k * 128 + 64 + c] = Wb[i];
    }
    for (int i = tid; i < 64 * 64; i += 256) {
        int r = i >> 6, k = i & 63;
        int gr = row0 + r;
        Xs[k][r] = (gr < M) ? X[(size_t)gr * 64 + k] : 0.f;
    }
    __syncthreads();
    int tr = (tid & 15) * 4;
    int tc = (tid >> 4) * 8;   // 0..120, never crosses the 64-col boundary
    float acc[4][8] = {};
#pragma unroll 8
    for (int k = 0; k < 64; ++k) {
        float4 xv = *(const float4*)&Xs[k][tr];
        float4 w0 = *(const float4*)&Ws[k * 128 + tc];
        float4 w1 = *(const float4*)&Ws[k * 128 + tc + 4];
        float x0 = xv.x, x1 = xv.y, x2 = xv.z, x3 = xv.w;
        acc[0][0] += x0 * w0.x; acc[0][1] += x0 * w0.y; acc[0][2] += x0 * w0.z; acc[0][3] += x0 * w0.w;
        acc[0][4] += x0 * w1.x; acc[0][5] += x0 * w1.y; acc[0][6] += x0 * w1.z; acc[0][7] += x0 * w1.w;
        acc[1][0] += x1 * w0.x; acc[1][1] += x1 * w0.y; acc[1][2] += x1 * w0.z; acc[1][3] += x1 * w0.w;
        acc[1][4] += x1 * w1.x; acc[1][5] += x1 * w1.y; acc[1][6] += x1 * w1.z; acc[1][7] += x1 * w1.w;
        acc[2][0] += x2 * w0.x; acc[2][1] += x2 * w0.y; acc[2][2] += x2 * w0.z; acc[2][3] += x2 * w0.w;
        acc[2][4] += x2 * w1.x; acc[2][5] += x2 * w1.y; acc[2][6] += x2 * w1.z; acc[2][7] += x2 * w1.w;
        acc[3][0] += x3 * w0.x; acc[3][1] += x3 * w0.y; acc[3][2] += x3 * w0.z; acc[3][3] += x3 * w0.w;
        acc[3][4] += x3 * w1.x; acc[3][5] += x3 * w1.y; acc[3][6] += x3 * w1.z; acc[3][7] += x3 * w1.w;
    }
    float* Y = (tc < 64) ? Ya : Yb;
    int c0 = tc & 63;
#pragma unroll
    for (int r = 0; r < 4; ++r) {
        int gr = row0 + tr + r;
        if (gr < M) {
            *(float4*)&Y[(size_t)gr * 64 + c0]     = make_float4(acc[r][0], acc[r][1], acc[r][2], acc[r][3]);
            *(float4*)&Y[(size_t)gr * 64 + c0 + 4] = make_float4(acc[r][4], acc[r][5], acc[r][6], acc[r][7]);
        }
    }
}

// ---------------- 64x64 weight collapse: OutW = A @ Wd1[brow0:+64,:], outc = bvec@slice (+addb) ----------------
__global__ __launch_bounds__(256) void wcollapse(
    const float* __restrict__ A, const float* __restrict__ Wd1, int brow0,
    const float* __restrict__ bvec, const float* __restrict__ addb,
    float* __restrict__ OutW, float* __restrict__ outc)
{
    __shared__ float As[64 * 64], Bs[64 * 64];
    int tid = threadIdx.x;
    for (int i = tid; i < 4096; i += 256) {
        As[i] = A[i];
        Bs[i] = Wd1[(size_t)(brow0 + (i >> 6)) * 64 + (i & 63)];
    }
    __syncthreads();
    int r = tid >> 2, c0 = (tid & 3) * 16;
    float acc[16] = {};
    for (int k = 0; k < 64; ++k) {
        float a = As[r * 64 + k];
        const float* bp = &Bs[k * 64 + c0];
#pragma unroll
        for (int j = 0; j < 16; ++j) acc[j] += a * bp[j];
    }
#pragma unroll
    for (int j = 0; j < 16; ++j) OutW[r * 64 + c0 + j] = acc[j];
    if (tid < 64) {
        float s = addb ? addb[tid] : 0.f;
        for (int k = 0; k < 64; ++k) s += bvec[k] * Bs[k * 64 + tid];
        outc[tid] = s;
    }
}

// ---------------- edge decoder: out[e] = bd2 + sum_lane relu(Au[ls]+Am[ld]) * Wd2 ----------------
__global__ __launch_bounds__(256) void edge_dec(
    const float* __restrict__ Au, const float* __restrict__ Am,
    const int* __restrict__ ls, const int* __restrict__ ld,
    const float* __restrict__ Wd2, const float* __restrict__ bd2,
    float* __restrict__ out, int L)
{
    int e = blockIdx.x * 4 + (threadIdx.x >> 6);
    if (e >= L) return;
    int lane = threadIdx.x & 63;
    float v = Au[(size_t)ls[e] * 64 + lane] + Am[(size_t)ld[e] * 64 + lane];
    v = fmaxf(v, 0.f) * Wd2[lane];
#pragma unroll
    for (int m = 32; m >= 1; m >>= 1) v += __shfl_xor(v, m, 64);
    if (lane == 0) out[e] = v + bd2[0];
}

// ---------------- host launcher ----------------
extern "C" void kernel_launch(void* const* d_in, const int* in_sizes, int n_in,
                              void* d_out, int out_size, void* d_ws, size_t ws_size,
                              hipStream_t stream)
{
    const float* x_user  = (const float*)d_in[0];
    const float* x_movie = (const float*)d_in[1];
    const int*   esrc    = (const int*)d_in[2];
    const int*   edst    = (const int*)d_in[3];
    const int*   lsrc    = (const int*)d_in[4];
    const int*   ldst    = (const int*)d_in[5];
    const float* W1ul = (const float*)d_in[6];
    const float* b1u  = (const float*)d_in[7];
    const float* W1ur = (const float*)d_in[8];
    const float* W1ml = (const float*)d_in[9];
    const float* b1m  = (const float*)d_in[10];
    const float* W1mr = (const float*)d_in[11];
    const float* W2ul = (const float*)d_in[12];
    const float* b2u  = (const float*)d_in[13];
    const float* W2ur = (const float*)d_in[14];
    const float* W2ml = (const float*)d_in[15];
    const float* b2m  = (const float*)d_in[16];
    const float* W2mr = (const float*)d_in[17];
    const float* Wd1  = (const float*)d_in[18];
    const float* bd1  = (const float*)d_in[19];
    const float* Wd2  = (const float*)d_in[20];
    const float* bd2  = (const float*)d_in[21];
    float* out = (float*)d_out;

    const int NU = in_sizes[0] / 128;
    const int NM = in_sizes[1] / 128;
    const int E  = in_sizes[2];
    const int L  = in_sizes[4];

    char* ws = (char*)d_ws;
    const size_t SU = (size_t)NU * 64 * 4;
    const size_t SM = (size_t)NM * 64 * 4;
    float* U0 = (float*)(ws + 0);
    float* U1 = (float*)(ws + SU);
    float* U2 = (float*)(ws + 2 * SU);
    float* M0 = (float*)(ws + 3 * SU);
    float* M1 = (float*)(ws + 3 * SU + SM);
    float* M2 = (float*)(ws + 3 * SU + 2 * SM);
    size_t o = 3 * SU + 3 * SM;
    auto align256 = [](size_t x) { return (x + 255) & ~(size_t)255; };
    int* gcm = (int*)(ws + o); o = align256(o + (size_t)(NBM + NBU) * 4);
    int* gcu = gcm + NBM;
    uint32_t* Bm = (uint32_t*)(ws + o); o = align256(o + (size_t)NBM * CAPM * 4);
    uint32_t* Bu = (uint32_t*)(ws + o); o = align256(o + (size_t)NBU * CAPU * 4);
    float* Wxu = (float*)(ws + o); o = align256(o + 4096 * 4);  // W2ml @ Wd1_top
    float* Wyu = (float*)(ws + o); o = align256(o + 4096 * 4);  // W2mr @ Wd1_top
    float* Wxm = (float*)(ws + o); o = align256(o + 4096 * 4);  // W2ul @ Wd1_bot
    float* Wym = (float*)(ws + o); o = align256(o + 4096 * 4);  // W2ur @ Wd1_bot
    float* cu  = (float*)(ws + o); o = align256(o + 64 * 4);    // b2m@Wd1_top + bd1
    float* cm  = (float*)(ws + o); o = align256(o + 64 * 4);    // b2u@Wd1_bot
    float* dump = (float*)(ws + o); o = align256(o + 64 * 4);

    // ---- bin edges into bucket-major lists (both directions) ----
    hipMemsetAsync(gcm, 0, (size_t)(NBM + NBU) * 4, stream);
    int nbins = (E + 8191) / 8192;
    bin_kernel<<<nbins, 256, 0, stream>>>(esrc, edst, E, gcm, gcu, Bm, Bu);

    // ---- decoder weight collapse (tiny) ----
    wcollapse<<<1, 256, 0, stream>>>(W2ml, Wd1, 0,  b2m, bd1,     Wxu, cu);
    wcollapse<<<1, 256, 0, stream>>>(W2mr, Wd1, 0,  b2m, nullptr, Wyu, dump);
    wcollapse<<<1, 256, 0, stream>>>(W2ul, Wd1, 64, b2u, nullptr, Wxm, cm);
    wcollapse<<<1, 256, 0, stream>>>(W2ur, Wd1, 64, b2u, nullptr, Wym, dump);

    int gu = (NU + 63) / 64, gm = (NM + 63) / 64;

    // ---- layer 1: pre-multiplied tables + self terms ----
    gemm_tile<128><<<gu, 256, 0, stream>>>(x_user,  W1ul, U0, NU);  // gathered by movie agg
    gemm_tile<128><<<gu, 256, 0, stream>>>(x_user,  W1mr, U1, NU);  // self term for h_u
    gemm_tile<128><<<gm, 256, 0, stream>>>(x_movie, W1ml, M0, NM);  // gathered by user agg
    gemm_tile<128><<<gm, 256, 0, stream>>>(x_movie, W1ur, M1, NM);  // self term for h_m

    agg_bucket<1><<<NBM, 256, 0, stream>>>(Bm, gcm, CAPM, U0, M1, b1u, M2, NM); // h_m
    agg_bucket<1><<<NBU, 256, 0, stream>>>(Bu, gcu, CAPU, M0, U1, b1m, U2, NU); // h_u

    // ---- layer 2 with decoder-collapsed weights (dual GEMMs: h read once) ----
    gemm64_dual<<<gm, 256, 0, stream>>>(M2, Wxu, Wym, M0, M1, NM); // G_m, S_m
    gemm64_dual<<<gu, 256, 0, stream>>>(U2, Wyu, Wxm, U0, U1, NU); // S_u, G_u

    agg_bucket<0><<<NBU, 256, 0, stream>>>(Bu, gcu, CAPU, M0, U0, cu, U2, NU); // Au
    agg_bucket<0><<<NBM, 256, 0, stream>>>(Bm, gcm, CAPM, U1, M1, cm, M2, NM); // Am

    // ---- edge decoder ----
    int gl = (L + 3) / 4;
    edge_dec<<<gl, 256, 0, stream>>>(U2, M2, lsrc, ldst, Wd2, bd2, out, L);
}

// Round 4
// 1106.177 us; speedup vs baseline: 3.4459x; 3.4459x over previous
//
#include <hip/hip_runtime.h>
#include <stdint.h>

#define BW   128      // nodes per bucket
#define NBM  625      // movie buckets  (80000/128)
#define NBU  1563     // user buckets   (ceil 200000/128)
#define CAPM 4096     // per-bucket capacity, movie (avg 3200, +15 sigma)
#define CAPU 2048     // per-bucket capacity, user  (avg 1280, +21 sigma)

// ---------------- edge binning: bucket-major edge lists, both directions ----------------
// Bm record: (dst&127)<<24 | src   (bucket = dst>>7)
// Bu record: (src&127)<<24 | dst   (bucket = src>>7)
__global__ __launch_bounds__(256) void bin_kernel(
    const int* __restrict__ src, const int* __restrict__ dst, int E,
    int* __restrict__ gcm, int* __restrict__ gcu,
    uint32_t* __restrict__ Bm, uint32_t* __restrict__ Bu)
{
    __shared__ int hm[NBM], hu[NBU];
    const int CH = 8192;
    int e0 = blockIdx.x * CH;
    int e1 = min(e0 + CH, E);
    int tid = threadIdx.x;
    for (int b = tid; b < NBM; b += 256) hm[b] = 0;
    for (int b = tid; b < NBU; b += 256) hu[b] = 0;
    __syncthreads();
    for (int i = e0 + tid; i < e1; i += 256) {
        atomicAdd(&hm[dst[i] >> 7], 1);
        atomicAdd(&hu[src[i] >> 7], 1);
    }
    __syncthreads();
    for (int b = tid; b < NBM; b += 256) { int c = hm[b]; hm[b] = c ? atomicAdd(&gcm[b], c) : 0; }
    for (int b = tid; b < NBU; b += 256) { int c = hu[b]; hu[b] = c ? atomicAdd(&gcu[b], c) : 0; }
    __syncthreads();
    for (int i = e0 + tid; i < e1; i += 256) {
        int d = dst[i], s = src[i];
        int bm = d >> 7, bu = s >> 7;
        int pm = atomicAdd(&hm[bm], 1);
        if (pm < CAPM) Bm[(size_t)bm * CAPM + pm] = ((uint32_t)(d & 127) << 24) | (uint32_t)s;
        int pu = atomicAdd(&hu[bu], 1);
        if (pu < CAPU) Bu[(size_t)bu * CAPU + pu] = ((uint32_t)(s & 127) << 24) | (uint32_t)d;
    }
}

// ---------------- per-bucket counting sort (in LDS) -> node-ordered payload + local offsets ----------------
template<int CAP>
__global__ __launch_bounds__(256) void sort_bucket(
    uint32_t* __restrict__ B, const int* __restrict__ gcnt, int* __restrict__ loff)
{
    __shared__ uint32_t rec[CAP];
    __shared__ uint32_t srt[CAP];
    __shared__ int hist[BW];
    __shared__ int hoff[BW + 1];
    __shared__ int cur[BW];
    int b = blockIdx.x, tid = threadIdx.x;
    int cnt = min(gcnt[b], CAP);
    uint32_t* bp = B + (size_t)b * CAP;
    for (int i = tid; i < cnt; i += 256) rec[i] = bp[i];
    if (tid < BW) hist[tid] = 0;
    __syncthreads();
    for (int i = tid; i < cnt; i += 256) atomicAdd(&hist[rec[i] >> 24], 1);
    __syncthreads();
    if (tid == 0) {
        int s = 0;
        for (int i = 0; i < BW; ++i) { hoff[i] = s; s += hist[i]; }
        hoff[BW] = s;
    }
    __syncthreads();
    if (tid < BW) cur[tid] = hoff[tid];
    __syncthreads();
    for (int i = tid; i < cnt; i += 256) {
        uint32_t r = rec[i];
        int pos = atomicAdd(&cur[r >> 24], 1);
        srt[pos] = r & 0xFFFFFFu;   // keep payload only
    }
    __syncthreads();
    for (int i = tid; i < cnt; i += 256) bp[i] = srt[i];
    for (int i = tid; i <= BW; i += 256) loff[(size_t)b * (BW + 1) + i] = hoff[i];
}

// ---------------- wave-per-node mean-aggregate + bias + self (+relu) ----------------
template<int RELU>
__global__ __launch_bounds__(256) void agg_csr(
    const uint32_t* __restrict__ B, const int* __restrict__ loff, int cap,
    const float* __restrict__ table, const float* __restrict__ self,
    const float* __restrict__ bias, float* __restrict__ out, int n_nodes)
{
    int node = blockIdx.x * 4 + (threadIdx.x >> 6);
    if (node >= n_nodes) return;
    int lane = threadIdx.x & 63;
    int b = node >> 7, l = node & 127;
    const int* lo = loff + (size_t)b * (BW + 1);
    int beg = lo[l], end = lo[l + 1];
    const uint32_t* bp = B + (size_t)b * cap;
    float acc = 0.f;
    int p = beg;
    for (; p + 8 <= end; p += 8) {
        uint32_t r0 = bp[p], r1 = bp[p+1], r2 = bp[p+2], r3 = bp[p+3];
        uint32_t r4 = bp[p+4], r5 = bp[p+5], r6 = bp[p+6], r7 = bp[p+7];
        acc += table[(size_t)r0 * 64 + lane];
        acc += table[(size_t)r1 * 64 + lane];
        acc += table[(size_t)r2 * 64 + lane];
        acc += table[(size_t)r3 * 64 + lane];
        acc += table[(size_t)r4 * 64 + lane];
        acc += table[(size_t)r5 * 64 + lane];
        acc += table[(size_t)r6 * 64 + lane];
        acc += table[(size_t)r7 * 64 + lane];
    }
    for (; p < end; ++p) acc += table[(size_t)bp[p] * 64 + lane];
    int deg = end - beg;
    float inv = 1.f / (float)(deg > 0 ? deg : 1);
    float v = acc * inv + bias[lane] + self[(size_t)node * 64 + lane];
    if (RELU) v = fmaxf(v, 0.f);
    out[(size_t)node * 64 + lane] = v;
}

// ---------------- tiled GEMM: Y[M,64] = X[M,K] @ W[K,64] ----------------
template<int K>
__global__ __launch_bounds__(256) void gemm_tile(
    const float* __restrict__ X, const float* __restrict__ W,
    float* __restrict__ Y, int M)
{
    __shared__ float Ws[K * 64];
    __shared__ float Xs[K][68];
    int tid = threadIdx.x;
    int row0 = blockIdx.x * 64;
    for (int i = tid; i < K * 64; i += 256) Ws[i] = W[i];
    for (int i = tid; i < 64 * K; i += 256) {
        int r = i / K, k = i - r * K;
        int gr = row0 + r;
        Xs[k][r] = (gr < M) ? X[(size_t)gr * K + k] : 0.f;
    }
    __syncthreads();
    int tr = (tid & 15) * 4;
    int tc = (tid >> 4) * 4;
    float acc[4][4] = {};
#pragma unroll 8
    for (int k = 0; k < K; ++k) {
        float4 xv = *(const float4*)&Xs[k][tr];
        float4 wv = *(const float4*)&Ws[k * 64 + tc];
        acc[0][0] += xv.x * wv.x; acc[0][1] += xv.x * wv.y; acc[0][2] += xv.x * wv.z; acc[0][3] += xv.x * wv.w;
        acc[1][0] += xv.y * wv.x; acc[1][1] += xv.y * wv.y; acc[1][2] += xv.y * wv.z; acc[1][3] += xv.y * wv.w;
        acc[2][0] += xv.z * wv.x; acc[2][1] += xv.z * wv.y; acc[2][2] += xv.z * wv.z; acc[2][3] += xv.z * wv.w;
        acc[3][0] += xv.w * wv.x; acc[3][1] += xv.w * wv.y; acc[3][2] += xv.w * wv.z; acc[3][3] += xv.w * wv.w;
    }
#pragma unroll
    for (int r = 0; r < 4; ++r) {
        int gr = row0 + tr + r;
        if (gr < M) {
            float4 o = make_float4(acc[r][0], acc[r][1], acc[r][2], acc[r][3]);
            *(float4*)&Y[(size_t)gr * 64 + tc] = o;
        }
    }
}

// ---------------- dual GEMM: Ya = X@Wa, Yb = X@Wb  (K=64, X read once) ----------------
__global__ __launch_bounds__(256) void gemm64_dual(
    const float* __restrict__ X, const float* __restrict__ Wa, const float* __restrict__ Wb,
    float* __restrict__ Ya, float* __restrict__ Yb, int M)
{
    __shared__ float Ws[64 * 128];
    __shared__ float Xs[64][68];
    int tid = threadIdx.x;
    int row0 = blockIdx.x * 64;
    for (int i = tid; i < 64 * 64; i += 256) {
        int k = i >> 6, c = i & 63;
        Ws[k * 128 + c] = Wa[i];
        Ws[k * 128 + 64 + c] = Wb[i];
    }
    for (int i = tid; i < 64 * 64; i += 256) {
        int r = i >> 6, k = i & 63;
        int gr = row0 + r;
        Xs[k][r] = (gr < M) ? X[(size_t)gr * 64 + k] : 0.f;
    }
    __syncthreads();
    int tr = (tid & 15) * 4;
    int tc = (tid >> 4) * 8;
    float acc[4][8] = {};
#pragma unroll 8
    for (int k = 0; k < 64; ++k) {
        float4 xv = *(const float4*)&Xs[k][tr];
        float4 w0 = *(const float4*)&Ws[k * 128 + tc];
        float4 w1 = *(const float4*)&Ws[k * 128 + tc + 4];
        float x0 = xv.x, x1 = xv.y, x2 = xv.z, x3 = xv.w;
        acc[0][0] += x0 * w0.x; acc[0][1] += x0 * w0.y; acc[0][2] += x0 * w0.z; acc[0][3] += x0 * w0.w;
        acc[0][4] += x0 * w1.x; acc[0][5] += x0 * w1.y; acc[0][6] += x0 * w1.z; acc[0][7] += x0 * w1.w;
        acc[1][0] += x1 * w0.x; acc[1][1] += x1 * w0.y; acc[1][2] += x1 * w0.z; acc[1][3] += x1 * w0.w;
        acc[1][4] += x1 * w1.x; acc[1][5] += x1 * w1.y; acc[1][6] += x1 * w1.z; acc[1][7] += x1 * w1.w;
        acc[2][0] += x2 * w0.x; acc[2][1] += x2 * w0.y; acc[2][2] += x2 * w0.z; acc[2][3] += x2 * w0.w;
        acc[2][4] += x2 * w1.x; acc[2][5] += x2 * w1.y; acc[2][6] += x2 * w1.z; acc[2][7] += x2 * w1.w;
        acc[3][0] += x3 * w0.x; acc[3][1] += x3 * w0.y; acc[3][2] += x3 * w0.z; acc[3][3] += x3 * w0.w;
        acc[3][4] += x3 * w1.x; acc[3][5] += x3 * w1.y; acc[3][6] += x3 * w1.z; acc[3][7] += x3 * w1.w;
    }
    float* Y = (tc < 64) ? Ya : Yb;
    int c0 = tc & 63;
#pragma unroll
    for (int r = 0; r < 4; ++r) {
        int gr = row0 + tr + r;
        if (gr < M) {
            *(float4*)&Y[(size_t)gr * 64 + c0]     = make_float4(acc[r][0], acc[r][1], acc[r][2], acc[r][3]);
            *(float4*)&Y[(size_t)gr * 64 + c0 + 4] = make_float4(acc[r][4], acc[r][5], acc[r][6], acc[r][7]);
        }
    }
}

// ---------------- 64x64 weight collapse: OutW = A @ Wd1[brow0:+64,:], outc = bvec@slice (+addb) ----------------
__global__ __launch_bounds__(256) void wcollapse(
    const float* __restrict__ A, const float* __restrict__ Wd1, int brow0,
    const float* __restrict__ bvec, const float* __restrict__ addb,
    float* __restrict__ OutW, float* __restrict__ outc)
{
    __shared__ float As[64 * 64], Bs[64 * 64];
    int tid = threadIdx.x;
    for (int i = tid; i < 4096; i += 256) {
        As[i] = A[i];
        Bs[i] = Wd1[(size_t)(brow0 + (i >> 6)) * 64 + (i & 63)];
    }
    __syncthreads();
    int r = tid >> 2, c0 = (tid & 3) * 16;
    float acc[16] = {};
    for (int k = 0; k < 64; ++k) {
        float a = As[r * 64 + k];
        const float* bp = &Bs[k * 64 + c0];
#pragma unroll
        for (int j = 0; j < 16; ++j) acc[j] += a * bp[j];
    }
#pragma unroll
    for (int j = 0; j < 16; ++j) OutW[r * 64 + c0 + j] = acc[j];
    if (tid < 64) {
        float s = addb ? addb[tid] : 0.f;
        for (int k = 0; k < 64; ++k) s += bvec[k] * Bs[k * 64 + tid];
        outc[tid] = s;
    }
}

// ---------------- edge decoder: out[e] = bd2 + sum_lane relu(Au[ls]+Am[ld]) * Wd2 ----------------
__global__ __launch_bounds__(256) void edge_dec(
    const float* __restrict__ Au, const float* __restrict__ Am,
    const int* __restrict__ ls, const int* __restrict__ ld,
    const float* __restrict__ Wd2, const float* __restrict__ bd2,
    float* __restrict__ out, int L)
{
    int e = blockIdx.x * 4 + (threadIdx.x >> 6);
    if (e >= L) return;
    int lane = threadIdx.x & 63;
    float v = Au[(size_t)ls[e] * 64 + lane] + Am[(size_t)ld[e] * 64 + lane];
    v = fmaxf(v, 0.f) * Wd2[lane];
#pragma unroll
    for (int m = 32; m >= 1; m >>= 1) v += __shfl_xor(v, m, 64);
    if (lane == 0) out[e] = v + bd2[0];
}

// ---------------- host launcher ----------------
extern "C" void kernel_launch(void* const* d_in, const int* in_sizes, int n_in,
                              void* d_out, int out_size, void* d_ws, size_t ws_size,
                              hipStream_t stream)
{
    const float* x_user  = (const float*)d_in[0];
    const float* x_movie = (const float*)d_in[1];
    const int*   esrc    = (const int*)d_in[2];
    const int*   edst    = (const int*)d_in[3];
    const int*   lsrc    = (const int*)d_in[4];
    const int*   ldst    = (const int*)d_in[5];
    const float* W1ul = (const float*)d_in[6];
    const float* b1u  = (const float*)d_in[7];
    const float* W1ur = (const float*)d_in[8];
    const float* W1ml = (const float*)d_in[9];
    const float* b1m  = (const float*)d_in[10];
    const float* W1mr = (const float*)d_in[11];
    const float* W2ul = (const float*)d_in[12];
    const float* b2u  = (const float*)d_in[13];
    const float* W2ur = (const float*)d_in[14];
    const float* W2ml = (const float*)d_in[15];
    const float* b2m  = (const float*)d_in[16];
    const float* W2mr = (const float*)d_in[17];
    const float* Wd1  = (const float*)d_in[18];
    const float* bd1  = (const float*)d_in[19];
    const float* Wd2  = (const float*)d_in[20];
    const float* bd2  = (const float*)d_in[21];
    float* out = (float*)d_out;

    const int NU = in_sizes[0] / 128;
    const int NM = in_sizes[1] / 128;
    const int E  = in_sizes[2];
    const int L  = in_sizes[4];

    char* ws = (char*)d_ws;
    const size_t SU = (size_t)NU * 64 * 4;
    const size_t SM = (size_t)NM * 64 * 4;
    float* U0 = (float*)(ws + 0);
    float* U1 = (float*)(ws + SU);
    float* U2 = (float*)(ws + 2 * SU);
    float* M0 = (float*)(ws + 3 * SU);
    float* M1 = (float*)(ws + 3 * SU + SM);
    float* M2 = (float*)(ws + 3 * SU + 2 * SM);
    size_t o = 3 * SU + 3 * SM;
    auto align256 = [](size_t x) { return (x + 255) & ~(size_t)255; };
    int* gcm = (int*)(ws + o); o = align256(o + (size_t)(NBM + NBU) * 4);
    int* gcu = gcm + NBM;
    uint32_t* Bm = (uint32_t*)(ws + o); o = align256(o + (size_t)NBM * CAPM * 4);
    uint32_t* Bu = (uint32_t*)(ws + o); o = align256(o + (size_t)NBU * CAPU * 4);
    int* loffm = (int*)(ws + o); o = align256(o + (size_t)NBM * (BW + 1) * 4);
    int* loffu = (int*)(ws + o); o = align256(o + (size_t)NBU * (BW + 1) * 4);
    float* Wxu = (float*)(ws + o); o = align256(o + 4096 * 4);  // W2ml @ Wd1_top
    float* Wyu = (float*)(ws + o); o = align256(o + 4096 * 4);  // W2mr @ Wd1_top
    float* Wxm = (float*)(ws + o); o = align256(o + 4096 * 4);  // W2ul @ Wd1_bot
    float* Wym = (float*)(ws + o); o = align256(o + 4096 * 4);  // W2ur @ Wd1_bot
    float* cu  = (float*)(ws + o); o = align256(o + 64 * 4);    // b2m@Wd1_top + bd1
    float* cm  = (float*)(ws + o); o = align256(o + 64 * 4);    // b2u@Wd1_bot
    float* dump = (float*)(ws + o); o = align256(o + 64 * 4);

    // ---- bin edges into bucket-major lists, then per-bucket counting sort ----
    hipMemsetAsync(gcm, 0, (size_t)(NBM + NBU) * 4, stream);
    int nbins = (E + 8191) / 8192;
    bin_kernel<<<nbins, 256, 0, stream>>>(esrc, edst, E, gcm, gcu, Bm, Bu);
    sort_bucket<CAPM><<<NBM, 256, 0, stream>>>(Bm, gcm, loffm);
    sort_bucket<CAPU><<<NBU, 256, 0, stream>>>(Bu, gcu, loffu);

    // ---- decoder weight collapse (tiny) ----
    wcollapse<<<1, 256, 0, stream>>>(W2ml, Wd1, 0,  b2m, bd1,     Wxu, cu);
    wcollapse<<<1, 256, 0, stream>>>(W2mr, Wd1, 0,  b2m, nullptr, Wyu, dump);
    wcollapse<<<1, 256, 0, stream>>>(W2ul, Wd1, 64, b2u, nullptr, Wxm, cm);
    wcollapse<<<1, 256, 0, stream>>>(W2ur, Wd1, 64, b2u, nullptr, Wym, dump);

    int gu = (NU + 63) / 64, gm = (NM + 63) / 64;

    // ---- layer 1: pre-multiplied tables + self terms ----
    gemm_tile<128><<<gu, 256, 0, stream>>>(x_user,  W1ul, U0, NU);  // gathered by movie agg
    gemm_tile<128><<<gu, 256, 0, stream>>>(x_user,  W1mr, U1, NU);  // self term for h_u
    gemm_tile<128><<<gm, 256, 0, stream>>>(x_movie, W1ml, M0, NM);  // gathered by user agg
    gemm_tile<128><<<gm, 256, 0, stream>>>(x_movie, W1ur, M1, NM);  // self term for h_m

    agg_csr<1><<<(NM + 3) / 4, 256, 0, stream>>>(Bm, loffm, CAPM, U0, M1, b1u, M2, NM); // h_m
    agg_csr<1><<<(NU + 3) / 4, 256, 0, stream>>>(Bu, loffu, CAPU, M0, U1, b1m, U2, NU); // h_u

    // ---- layer 2 with decoder-collapsed weights (dual GEMMs: h read once) ----
    gemm64_dual<<<gm, 256, 0, stream>>>(M2, Wxu, Wym, M0, M1, NM); // G_m, S_m
    gemm64_dual<<<gu, 256, 0, stream>>>(U2, Wyu, Wxm, U0, U1, NU); // S_u, G_u

    agg_csr<0><<<(NU + 3) / 4, 256, 0, stream>>>(Bu, loffu, CAPU, M0, U0, cu, U2, NU); // Au
    agg_csr<0><<<(NM + 3) / 4, 256, 0, stream>>>(Bm, loffm, CAPM, U1, M1, cm, M2, NM); // Am

    // ---- edge decoder ----
    int gl = (L + 3) / 4;
    edge_dec<<<gl, 256, 0, stream>>>(U2, M2, lsrc, ldst, Wd2, bd2, out, L);
}